// Round 5
// baseline (579.839 us; speedup 1.0000x reference)
//
#include <hip/hip_runtime.h>
#include <stdint.h>

#define NB   4096
#define DIN  1024
#define DOUT 1024
#define NL   32
#define KPW  (DIN * NL)     // 32768
#define KTOT (KPW + 64)     // 32832 (pad: 32 bias cols + 32 zero cols)
#define BKT  64
#define KITERS (KTOT / BKT) // 513
#define NSPLIT 8            // split-K ways: 65 + 7*64

typedef __attribute__((ext_vector_type(8))) short short8;          // 8 bf16 (A/B frag)
typedef __attribute__((ext_vector_type(8))) unsigned short ushort8;
typedef __attribute__((ext_vector_type(4))) float floatx4;         // C/D frag
typedef __attribute__((ext_vector_type(2))) float floatx2;

// float -> bf16 bits, round-to-nearest-even (finite inputs only)
__device__ __forceinline__ unsigned short f2bf(float v) {
    uint32_t u = __float_as_uint(v);
    return (unsigned short)((u + 0x7FFFu + ((u >> 16) & 1u)) >> 16);
}

// two floats -> packed bf16x2 by TRUNCATION (1x v_perm_b32); low half = a.
__device__ __forceinline__ uint32_t f2bf2_trunc(float a, float b) {
    return __builtin_amdgcn_perm(__float_as_uint(b), __float_as_uint(a), 0x07060302u);
}

// async global->LDS, 16B per lane; LDS dst = wave-uniform base + lane*16
__device__ __forceinline__ void async_ld16(const void* g, void* l) {
    __builtin_amdgcn_global_load_lds(
        (const __attribute__((address_space(1))) void*)g,
        (__attribute__((address_space(3))) void*)l, 16, 0, 0);
}

// ---------------------------------------------------------------------------
// Kernel 1: gating softmax -> g [NB][NL] fp32. One wave per row (4 rows/block).
// ---------------------------------------------------------------------------
__global__ __launch_bounds__(256) void gate_kernel(
    const float* __restrict__ x, const float* __restrict__ gw,
    const float* __restrict__ gb, float* __restrict__ g)
{
    const int wave = threadIdx.x >> 6;
    const int lane = threadIdx.x & 63;
    const int b = blockIdx.x * 4 + wave;
    const int l = lane & 31;
    const int c = lane >> 5;              // half-wave handles 512 of 1024 i's
    const float* xrow = x + (size_t)b * DIN;

    float p0 = 0.f, p1 = 0.f, p2 = 0.f, p3 = 0.f;
    const int i0 = c * 512;
    #pragma unroll 2
    for (int j = 0; j < 512; j += 4) {
        const int i = i0 + j;
        p0 = fmaf(xrow[i + 0], gw[(i + 0) * NL + l], p0);
        p1 = fmaf(xrow[i + 1], gw[(i + 1) * NL + l], p1);
        p2 = fmaf(xrow[i + 2], gw[(i + 2) * NL + l], p2);
        p3 = fmaf(xrow[i + 3], gw[(i + 3) * NL + l], p3);
    }
    float p = (p0 + p1) + (p2 + p3);
    p += __shfl_xor(p, 32);               // combine the two i-halves
    const float logit = p + gb[l];
    float m = logit;
    for (int off = 16; off > 0; off >>= 1) m = fmaxf(m, __shfl_xor(m, off));
    const float e = __expf(logit - m);
    float s = e;
    for (int off = 16; off > 0; off >>= 1) s += __shfl_xor(s, off);
    if (lane < NL) g[(size_t)b * NL + l] = e / s;
}

// ---------------------------------------------------------------------------
// Kernel 2: pw fp32 [1024,32768] (+ pb [1024,32]) -> bf16 pwb [1024, KTOT]
// ---------------------------------------------------------------------------
__global__ __launch_bounds__(256) void build_pwb(
    const float* __restrict__ pw, const float* __restrict__ pb,
    unsigned short* __restrict__ out)
{
    const int o = blockIdx.x;
    const int t = threadIdx.x;
    const float* src = pw + (size_t)o * KPW;
    unsigned short* dst = out + (size_t)o * KTOT;

    #pragma unroll 2
    for (int s = 0; s < 16; ++s) {
        const int k = (s * 256 + t) * 8;
        const float4 a = *(const float4*)(src + k);
        const float4 c = *(const float4*)(src + k + 4);
        ushort8 o8;
        o8[0] = f2bf(a.x); o8[1] = f2bf(a.y); o8[2] = f2bf(a.z); o8[3] = f2bf(a.w);
        o8[4] = f2bf(c.x); o8[5] = f2bf(c.y); o8[6] = f2bf(c.z); o8[7] = f2bf(c.w);
        *(ushort8*)(dst + k) = o8;
    }
    if (t < 8) {   // tail: 32 bias cols + 32 zeros
        ushort8 o8;
        #pragma unroll
        for (int j = 0; j < 8; ++j) {
            const int l = t * 8 + j;
            o8[j] = (l < NL) ? f2bf(pb[(size_t)o * NL + l]) : (unsigned short)0;
        }
        *(ushort8*)(dst + KPW + t * 8) = o8;
    }
}

// ---------------------------------------------------------------------------
// Kernel 3: C[b,o] += sum_k y[b,k]*pwb[o,k] with y built ON THE FLY in LDS:
//   y[b, i*32+l] = bf16(x[b,i]*g[b,l]);  bias iter (i=1024) uses x==1.
// 128x128 tile, BK=64, XOR-swizzled LDS (r2: conflicts 1e8->0).
// r5: split-K 4->8 (grid 2048). r4 post-mortem: GEMM is latency-bound at
// 3 blocks/CU (grid-limited); MfmaUtil 38 / VALU 23 / HBM 6% all idle.
// 5 resident blocks/CU (LDS cap) lets other blocks' MFMA cover each
// block's vmcnt(0) barrier drain. Each XCD owns one z-slice (B-panel ~1MB,
// x-slice ~2MB stay L2-resident).
// ---------------------------------------------------------------------------
__global__ __launch_bounds__(256, 4) void gemm_splitk(
    const float* __restrict__ X,            // x [NB][DIN] fp32
    const float* __restrict__ G,            // g [NB][NL]  fp32
    const unsigned short* __restrict__ Bw,  // pwb [DOUT][KTOT] bf16
    float* __restrict__ C)                  // [NB][DOUT], pre-zeroed
{
    __shared__ unsigned short As[128 * BKT];
    __shared__ unsigned short Bs[128 * BKT];

    const int t    = threadIdx.x;
    const int wave = t >> 6;
    const int lane = t & 63;

    // XCD-aware decode: 8 bn-blocks sharing one (bm,z) A-panel -> same XCD;
    // z == xcd so each XCD's L2 holds one B z-slice.
    const int id  = blockIdx.x;             // 0..2047
    const int xcd = id & 7;
    const int s_  = id >> 3;                // 0..255
    const int bn  = (s_ & 7) * 128;
    const int idx = xcd * 32 + (s_ >> 3);   // 0..255
    const int bm  = (idx & 31) * 128;
    const int z   = idx >> 5;               // 0..7
    const int it0 = z ? (64 * z + 1) : 0;   // splits: 65 + 7*64 = 513
    const int it1 = 64 * (z + 1) + 1;

    const int wm = (wave >> 1) * 64;
    const int wn = (wave & 1) * 64;
    const int ml   = lane & 15;
    const int quad = lane >> 4;
    const int xorm = ml & 7;

    // B staging via async DMA (swizzled source, as r2)
    const int row0 = t >> 3;
    const int uc   = (((t & 7) ^ ((t >> 3) & 7)) * 8);
    const unsigned short* Bg = Bw + (size_t)(bn + row0) * KTOT + uc + (size_t)it0 * BKT;
    unsigned short* Bl = Bs + wave * 512;   // + s*2048 per chunk; HW adds lane*16B

    // A on-the-fly build: thread t owns row r=t>>1, leaves lh=(t&1)*16..+15
    const int r   = t >> 1;                 // row 0..127
    const int lh  = (t & 1) * 16;           // leaf base 0 or 16
    const int rx  = r & 7;
    const float* xp = X + (size_t)(bm + r) * DIN;
    unsigned short* Aw = As + r * BKT;
    floatx2 gq2[8];                         // 16 gates as 8 float2 pairs
    {
        const float* gp = G + (size_t)(bm + r) * NL + lh;
        #pragma unroll
        for (int q = 0; q < 4; ++q) {
            const float4 v = *(const float4*)(gp + q * 4);
            gq2[q * 2 + 0] = (floatx2){v.x, v.y};
            gq2[q * 2 + 1] = (floatx2){v.z, v.w};
        }
    }

    floatx4 acc[4][4] = {};
    float2 xv = *(const float2*)(xp + min(it0 * 2, DIN - 2));

    for (int it = it0; it < it1; ++it) {
        // 1) B tile DMA (overlaps the VALU A-build below)
        #pragma unroll
        for (int s = 0; s < 4; ++s)
            async_ld16(Bg + (size_t)(s * 32) * KTOT, Bl + s * 2048);
        Bg += BKT;

        // 2) bias fixup (uniform branch; only it==512 hits it)
        const bool inb = (it * 2) < DIN;
        const float xa = inb ? xv.x : 1.0f;   // i=1024: y-col = g (pairs with pb)
        const float xb = inb ? xv.y : 0.0f;   // i=1025: zero pad
        // 3) prefetch next x (clamped; drained by the same pre-barrier wait)
        xv = *(const float2*)(xp + min((it + 1) * 2, DIN - 2));

        // 4) build 32 bf16 of As: paired muls + truncation pack (1 perm/pair)
        #pragma unroll
        for (int ii = 0; ii < 2; ++ii) {
            const float xs = ii ? xb : xa;
            const floatx2 xs2 = {xs, xs};
            #pragma unroll
            for (int j = 0; j < 2; ++j) {
                const floatx2 p0 = xs2 * gq2[j * 4 + 0];
                const floatx2 p1 = xs2 * gq2[j * 4 + 1];
                const floatx2 p2 = xs2 * gq2[j * 4 + 2];
                const floatx2 p3 = xs2 * gq2[j * 4 + 3];
                uint4 v;
                v.x = f2bf2_trunc(p0.x, p0.y);
                v.y = f2bf2_trunc(p1.x, p1.y);
                v.z = f2bf2_trunc(p2.x, p2.y);
                v.w = f2bf2_trunc(p3.x, p3.y);
                const int c = ii * 4 + (t & 1) * 2 + j;
                *(uint4*)(Aw + ((c ^ rx) * 8)) = v;
            }
        }
        __syncthreads();

        #pragma unroll
        for (int kk = 0; kk < 2; ++kk) {
            const int swz = ((kk * 4 + quad) ^ xorm) * 8;
            short8 af[4], bf[4];
            #pragma unroll
            for (int im = 0; im < 4; ++im)
                af[im] = *(const short8*)(As + (wm + im * 16 + ml) * BKT + swz);
            #pragma unroll
            for (int in = 0; in < 4; ++in)
                bf[in] = *(const short8*)(Bs + (wn + in * 16 + ml) * BKT + swz);
            #pragma unroll
            for (int im = 0; im < 4; ++im)
                #pragma unroll
                for (int in = 0; in < 4; ++in)
                    acc[im][in] = __builtin_amdgcn_mfma_f32_16x16x32_bf16(
                        af[im], bf[in], acc[im][in], 0, 0, 0);
        }
        __syncthreads();
    }

    // epilogue: C/D map col=lane&15, row=quad*4+reg (m89-verified); atomic for split-K
    #pragma unroll
    for (int im = 0; im < 4; ++im)
        #pragma unroll
        for (int in = 0; in < 4; ++in) {
            const int row = bm + wm + im * 16 + quad * 4;
            const int col = bn + wn + in * 16 + ml;
            #pragma unroll
            for (int rr = 0; rr < 4; ++rr)
                atomicAdd(&C[(size_t)(row + rr) * DOUT + col], acc[im][in][rr]);
        }
}

// ---------------------------------------------------------------------------
extern "C" void kernel_launch(void* const* d_in, const int* in_sizes, int n_in,
                              void* d_out, int out_size, void* d_ws, size_t ws_size,
                              hipStream_t stream) {
    const float* x  = (const float*)d_in[0];   // [4096,1024]
    const float* gw = (const float*)d_in[1];   // [1024,32]
    const float* gb = (const float*)d_in[2];   // [32]
    const float* pw = (const float*)d_in[3];   // [1024,1024,32]
    const float* pb = (const float*)d_in[4];   // [1024,32]
    float* out = (float*)d_out;                // [4096,1024]

    float* g            = (float*)d_ws;                               // 512 KB
    unsigned short* pwb = (unsigned short*)((char*)d_ws + (1 << 20)); // 67.2 MB
    // ws use: 1 MB + 1024*32832*2 = ~68.3 MB

    hipMemsetAsync(d_out, 0, (size_t)NB * DOUT * sizeof(float), stream);
    gate_kernel<<<NB / 4, 256, 0, stream>>>(x, gw, gb, g);
    build_pwb<<<DOUT, 256, 0, stream>>>(pw, pb, pwb);
    gemm_splitk<<<(DOUT / 128) * (NB / 128) * NSPLIT, 256, 0, stream>>>(x, g, pwb, out);
}

// Round 6
// 546.122 us; speedup vs baseline: 1.0617x; 1.0617x over previous
//
#include <hip/hip_runtime.h>
#include <stdint.h>

#define NB   4096
#define DIN  1024
#define DOUT 1024
#define NL   32
#define KPW  (DIN * NL)     // 32768
#define KTOT (KPW + 64)     // 32832 (pad: 32 bias cols + 32 zero cols)
#define BKT  64
#define KITERS (KTOT / BKT) // 513
#define NSPLIT 4            // split-K ways: 129+128+128+128 (r3 best: 311us)

typedef __attribute__((ext_vector_type(8))) short short8;          // 8 bf16 (A/B frag)
typedef __attribute__((ext_vector_type(8))) unsigned short ushort8;
typedef __attribute__((ext_vector_type(4))) float floatx4;         // C/D frag

// float -> bf16 bits, round-to-nearest-even (finite inputs only)
__device__ __forceinline__ unsigned short f2bf(float v) {
    uint32_t u = __float_as_uint(v);
    return (unsigned short)((u + 0x7FFFu + ((u >> 16) & 1u)) >> 16);
}

// two floats -> packed bf16x2 (RNE), low half = a (r3 config; r4's trunc pack
// regressed 311->326: A-build VALU is NOT on the critical path)
__device__ __forceinline__ uint32_t f2bf2(float a, float b) {
    uint32_t ua = __float_as_uint(a), ub = __float_as_uint(b);
    ua += 0x7FFFu + ((ua >> 16) & 1u);
    ub += 0x7FFFu + ((ub >> 16) & 1u);
    return __builtin_amdgcn_perm(ub, ua, 0x07060302u);  // {ub_hi16, ua_hi16}
}

// async global->LDS, 16B per lane; LDS dst = wave-uniform base + lane*16
__device__ __forceinline__ void async_ld16(const void* g, void* l) {
    __builtin_amdgcn_global_load_lds(
        (const __attribute__((address_space(1))) void*)g,
        (__attribute__((address_space(3))) void*)l, 16, 0, 0);
}

// ---------------------------------------------------------------------------
// Fused prep (ONE dispatch replaces memset + gate + build_pwb; r6):
//   blocks [0,1024)    : pw fp32 (+pb) -> bf16 pwb row
//   blocks [1024,2048) : gating softmax, 4 rows/block -> g fp32
//   blocks [2048,2112) : zero d_out (harness poisons it 0xAA each replay)
// Role branch is block-uniform. GEMM depends on all three via stream order.
// ---------------------------------------------------------------------------
__global__ __launch_bounds__(256) void prep_fused(
    const float* __restrict__ x, const float* __restrict__ gw,
    const float* __restrict__ gb, const float* __restrict__ pw,
    const float* __restrict__ pb, float* __restrict__ g,
    unsigned short* __restrict__ pwb, float* __restrict__ C)
{
    const int id = blockIdx.x;
    const int t  = threadIdx.x;

    if (id < DOUT) {
        // ---- role 1: pwb build (HBM-bound: 134MB read + 67MB write) ----
        const int o = id;
        const float* src = pw + (size_t)o * KPW;
        unsigned short* dst = pwb + (size_t)o * KTOT;
        #pragma unroll 2
        for (int s = 0; s < 16; ++s) {
            const int k = (s * 256 + t) * 8;
            const float4 a = *(const float4*)(src + k);
            const float4 c = *(const float4*)(src + k + 4);
            ushort8 o8;
            o8[0] = f2bf(a.x); o8[1] = f2bf(a.y); o8[2] = f2bf(a.z); o8[3] = f2bf(a.w);
            o8[4] = f2bf(c.x); o8[5] = f2bf(c.y); o8[6] = f2bf(c.z); o8[7] = f2bf(c.w);
            *(ushort8*)(dst + k) = o8;
        }
        if (t < 8) {   // tail: 32 bias cols + 32 zeros
            ushort8 o8;
            #pragma unroll
            for (int j = 0; j < 8; ++j) {
                const int l = t * 8 + j;
                o8[j] = (l < NL) ? f2bf(pb[(size_t)o * NL + l]) : (unsigned short)0;
            }
            *(ushort8*)(dst + KPW + t * 8) = o8;
        }
    } else if (id < DOUT + NB / 4) {
        // ---- role 2: gating softmax, one wave per row ----
        const int wave = t >> 6;
        const int lane = t & 63;
        const int b = (id - DOUT) * 4 + wave;
        const int l = lane & 31;
        const int c = lane >> 5;
        const float* xrow = x + (size_t)b * DIN;
        float p0 = 0.f, p1 = 0.f, p2 = 0.f, p3 = 0.f;
        const int i0 = c * 512;
        #pragma unroll 2
        for (int j = 0; j < 512; j += 4) {
            const int i = i0 + j;
            p0 = fmaf(xrow[i + 0], gw[(i + 0) * NL + l], p0);
            p1 = fmaf(xrow[i + 1], gw[(i + 1) * NL + l], p1);
            p2 = fmaf(xrow[i + 2], gw[(i + 2) * NL + l], p2);
            p3 = fmaf(xrow[i + 3], gw[(i + 3) * NL + l], p3);
        }
        float p = (p0 + p1) + (p2 + p3);
        p += __shfl_xor(p, 32);
        const float logit = p + gb[l];
        float m = logit;
        for (int off = 16; off > 0; off >>= 1) m = fmaxf(m, __shfl_xor(m, off));
        const float e = __expf(logit - m);
        float s = e;
        for (int off = 16; off > 0; off >>= 1) s += __shfl_xor(s, off);
        if (lane < NL) g[(size_t)b * NL + l] = e / s;
    } else {
        // ---- role 3: zero C (16MB / 64 blocks = 64 float4-iters/thread) ----
        const int zb = id - (DOUT + NB / 4);
        float4* dst = (float4*)C + (size_t)zb * (256 * 64) + t;
        const float4 z4 = {0.f, 0.f, 0.f, 0.f};
        #pragma unroll 4
        for (int s = 0; s < 64; ++s) dst[s * 256] = z4;
    }
}

// ---------------------------------------------------------------------------
// GEMM (exact r3 config — best measured: 311us, 886 TF, at the documented
// m97-structure plateau): C[b,o] += sum_k y[b,k]*pwb[o,k], y built on the fly
// in LDS (y[b,i*32+l] = bf16(x[b,i]*g[b,l]); bias iter i=1024 uses x==1).
// 128x128 tile, BK=64, split-K=4, XOR-swizzled LDS (r2: conflicts 1e8->0).
// Register budget: 64 VGPR + 64 AGPR = 128 -> 4 waves/SIMD -> 4 blocks/CU
// hard cap (r5 lesson: grid/split-K can't raise occupancy past this).
// ---------------------------------------------------------------------------
__global__ __launch_bounds__(256, 4) void gemm_splitk(
    const float* __restrict__ X,            // x [NB][DIN] fp32
    const float* __restrict__ G,            // g [NB][NL]  fp32
    const unsigned short* __restrict__ Bw,  // pwb [DOUT][KTOT] bf16
    float* __restrict__ C)                  // [NB][DOUT], pre-zeroed
{
    __shared__ unsigned short As[128 * BKT];
    __shared__ unsigned short Bs[128 * BKT];

    const int t    = threadIdx.x;
    const int wave = t >> 6;
    const int lane = t & 63;

    // XCD-aware decode: 8 bn-blocks sharing one (bm,z) A-panel -> same XCD L2
    const int id  = blockIdx.x;
    const int xcd = id & 7;
    const int s_  = id >> 3;               // 0..127
    const int bn  = (s_ & 7) * 128;
    const int idx = xcd * 16 + (s_ >> 3);  // 0..127
    const int bm  = (idx & 31) * 128;
    const int z   = idx >> 5;              // 0..3
    const int it0 = z * 128 + (z ? 1 : 0); // splits: 129+128+128+128
    const int it1 = (z + 1) * 128 + 1;

    const int wm = (wave >> 1) * 64;
    const int wn = (wave & 1) * 64;
    const int ml   = lane & 15;
    const int quad = lane >> 4;
    const int xorm = ml & 7;

    // B staging via async DMA (swizzled source, as r2)
    const int row0 = t >> 3;
    const int uc   = (((t & 7) ^ ((t >> 3) & 7)) * 8);
    const unsigned short* Bg = Bw + (size_t)(bn + row0) * KTOT + uc + (size_t)it0 * BKT;
    unsigned short* Bl = Bs + wave * 512;   // + s*2048 per chunk; HW adds lane*16B

    // A on-the-fly build: thread t owns row r=t>>1, leaves lh=(t&1)*16..+15
    const int r   = t >> 1;                 // row 0..127
    const int lh  = (t & 1) * 16;           // leaf base 0 or 16
    const int rx  = r & 7;
    const float* xp = X + (size_t)(bm + r) * DIN;
    unsigned short* Aw = As + r * BKT;
    float gq[16];
    {
        const float* gp = G + (size_t)(bm + r) * NL + lh;
        #pragma unroll
        for (int q = 0; q < 4; ++q) {
            const float4 v = *(const float4*)(gp + q * 4);
            gq[q * 4 + 0] = v.x; gq[q * 4 + 1] = v.y;
            gq[q * 4 + 2] = v.z; gq[q * 4 + 3] = v.w;
        }
    }

    floatx4 acc[4][4] = {};
    float2 xv = *(const float2*)(xp + min(it0 * 2, DIN - 2));

    for (int it = it0; it < it1; ++it) {
        // 1) B tile DMA (overlaps the VALU A-build below)
        #pragma unroll
        for (int s = 0; s < 4; ++s)
            async_ld16(Bg + (size_t)(s * 32) * KTOT, Bl + s * 2048);
        Bg += BKT;

        // 2) bias fixup (uniform branch; only it==512 hits it)
        const bool inb = (it * 2) < DIN;
        const float xa = inb ? xv.x : 1.0f;   // i=1024: y-col = g (pairs with pb)
        const float xb = inb ? xv.y : 0.0f;   // i=1025: zero pad
        // 3) prefetch next x (clamped; drained by the same pre-barrier wait)
        xv = *(const float2*)(xp + min((it + 1) * 2, DIN - 2));

        // 4) build 32 bf16 of As: rows fixed, chunks c = ii*4 + (t&1)*2 + j
        #pragma unroll
        for (int ii = 0; ii < 2; ++ii) {
            const float xs = ii ? xb : xa;
            #pragma unroll
            for (int j = 0; j < 2; ++j) {
                uint4 v;
                v.x = f2bf2(xs * gq[j * 8 + 0], xs * gq[j * 8 + 1]);
                v.y = f2bf2(xs * gq[j * 8 + 2], xs * gq[j * 8 + 3]);
                v.z = f2bf2(xs * gq[j * 8 + 4], xs * gq[j * 8 + 5]);
                v.w = f2bf2(xs * gq[j * 8 + 6], xs * gq[j * 8 + 7]);
                const int c = ii * 4 + (t & 1) * 2 + j;
                *(uint4*)(Aw + ((c ^ rx) * 8)) = v;
            }
        }
        __syncthreads();

        #pragma unroll
        for (int kk = 0; kk < 2; ++kk) {
            const int swz = ((kk * 4 + quad) ^ xorm) * 8;
            short8 af[4], bf[4];
            #pragma unroll
            for (int im = 0; im < 4; ++im)
                af[im] = *(const short8*)(As + (wm + im * 16 + ml) * BKT + swz);
            #pragma unroll
            for (int in = 0; in < 4; ++in)
                bf[in] = *(const short8*)(Bs + (wn + in * 16 + ml) * BKT + swz);
            #pragma unroll
            for (int im = 0; im < 4; ++im)
                #pragma unroll
                for (int in = 0; in < 4; ++in)
                    acc[im][in] = __builtin_amdgcn_mfma_f32_16x16x32_bf16(
                        af[im], bf[in], acc[im][in], 0, 0, 0);
        }
        __syncthreads();
    }

    // epilogue: C/D map col=lane&15, row=quad*4+reg (m89-verified); atomic for split-K
    #pragma unroll
    for (int im = 0; im < 4; ++im)
        #pragma unroll
        for (int in = 0; in < 4; ++in) {
            const int row = bm + wm + im * 16 + quad * 4;
            const int col = bn + wn + in * 16 + ml;
            #pragma unroll
            for (int rr = 0; rr < 4; ++rr)
                atomicAdd(&C[(size_t)(row + rr) * DOUT + col], acc[im][in][rr]);
        }
}

// ---------------------------------------------------------------------------
extern "C" void kernel_launch(void* const* d_in, const int* in_sizes, int n_in,
                              void* d_out, int out_size, void* d_ws, size_t ws_size,
                              hipStream_t stream) {
    const float* x  = (const float*)d_in[0];   // [4096,1024]
    const float* gw = (const float*)d_in[1];   // [1024,32]
    const float* gb = (const float*)d_in[2];   // [32]
    const float* pw = (const float*)d_in[3];   // [1024,1024,32]
    const float* pb = (const float*)d_in[4];   // [1024,32]
    float* out = (float*)d_out;                // [4096,1024]

    float* g            = (float*)d_ws;                               // 512 KB
    unsigned short* pwb = (unsigned short*)((char*)d_ws + (1 << 20)); // 67.2 MB
    // ws use: 1 MB + 1024*32832*2 = ~68.3 MB

    // One fused prep dispatch: pwb (1024 blocks) + gate (1024) + zero-C (64)
    prep_fused<<<DOUT + NB / 4 + 64, 256, 0, stream>>>(x, gw, gb, pw, pb, g, pwb, out);
    gemm_splitk<<<(DOUT / 128) * (NB / 128) * NSPLIT, 256, 0, stream>>>(x, g, pwb, out);
}